// Round 6
// baseline (249.254 us; speedup 1.0000x reference)
//
#include <hip/hip_runtime.h>
#include <stdint.h>

// DifferentiableSkeletonize on (2,1,256,256,256) binary fp32 mask.
// dilated = avgpool3(avgpool3(x)) -> separable per-axis double-box:
//   interior kernel [1,2,3,2,1]/9 (zero-extended); boundary planes (i=0,255)
//   subtract one extra center tap. n = integer numerator in [0,729].
// Pointwise tail reduces EXACTLY to an integer threshold:
//   out = (x==0 && n>=9) ? 1.0f : 0.0f   (verified, absmax 0)
//
// Two-phase, BW-shaped:
//   K1: d-axis (DPP) + w-axis marching window -> ws bytes (n_dw | x-bit).
//       TWO independent slab-chains per wave (2x MLP, 8 loads in flight),
//       dead tail loads removed (compile-time guard).
//   K2: TRANSPOSED decomposition: wave owns (slab=(bi,hi), 16-w chunk);
//       h-filter inputs are 5 wave-uniform slab rows (L3-served), stores
//       march along w -> contiguous 16KB write stream per wave (64KB per
//       block) instead of 64KB-strided 1KB writes. Write-locality fix.

typedef float  vfloat4 __attribute__((ext_vector_type(4)));

#define CH1 16          // w-outputs per chain in K1
#define NCH1 16         // 256 / CH1
#define BLOCKS_K1 1024  // 256 slab-pairs * 16 chunks / 4 waves

#define CW2 16          // w-outputs per wave in K2
#define NCW2 16         // 256 / CW2
#define BLOCKS_K2 2048  // 512 slabs * 16 chunks / 4 waves

// d-axis filter: lane ln owns bytes for d = 4ln..4ln+3. b = 4 packed x-bits.
// wave_shr1 (0x138): lane i <- i-1 (lane0 -> 0)  == shfl_up(b,1)
// wave_shl1 (0x130): lane i <- i+1 (lane63 -> 0) == shfl_down(b,1)
__device__ __forceinline__ uint32_t row_pack(uint32_t b, const int ln) {
    uint32_t up = (uint32_t)__builtin_amdgcn_update_dpp(
        0, (int)b, 0x138, 0xf, 0xf, true);
    uint32_t dn = (uint32_t)__builtin_amdgcn_update_dpp(
        0, (int)b, 0x130, 0xf, 0xf, true);
    uint64_t W = (uint64_t)(up >> 16) | ((uint64_t)b << 16)
               | ((uint64_t)(dn & 0xffffu) << 48);
    uint64_t S = W + ((W >> 8) << 1) + (W >> 16) * 3u + ((W >> 24) << 1) + (W >> 32);
    uint32_t n = (uint32_t)S;
    if (ln == 0)  n -= (b & 0xffu);        // d==0 boundary correction
    if (ln == 63) n -= (b & 0xff000000u);  // d==255
    return n | (b << 7);                   // x-bit -> bit7 of each byte
}

__device__ __forceinline__ uint32_t bits_of(const vfloat4 v) {
    return (v.x > 0.5f ? 0x1u : 0u) | (v.y > 0.5f ? 0x100u : 0u)
         | (v.z > 0.5f ? 0x10000u : 0u) | (v.w > 0.5f ? 0x1000000u : 0u);
}

// K1: fused d-axis + w-axis. One wave handles TWO slabs (independent chains).
// ws byte = n_dw (<=81) | x-bit(0x80).
__global__ __launch_bounds__(256) void skel_k1(const float* __restrict__ x,
                                               uint32_t* __restrict__ ws) {
    const int ln    = threadIdx.x & 63;
    const int wid   = (blockIdx.x << 2) | (threadIdx.x >> 6);  // 0..4095
    const int chunk = wid & (NCH1 - 1);
    const int sp    = wid >> 4;            // slab pair 0..255
    const int w0    = chunk * CH1;

    const vfloat4* xs[2] = {
        (const vfloat4*)(x + (size_t)(2 * sp)     * 65536),
        (const vfloat4*)(x + (size_t)(2 * sp + 1) * 65536)};
    uint32_t* os[2] = { ws + (size_t)(2 * sp)     * 16384,
                        ws + (size_t)(2 * sp + 1) * 16384 };

    auto ldx = [&](int c, int wi) -> vfloat4 {     // cached: halo reuse L2/L3
        int wc = wi < 0 ? 0 : (wi > 255 ? 255 : wi);
        return xs[c][wc * 64 + ln];
    };
    auto packb = [&](vfloat4 v, int wi) -> uint32_t {
        uint32_t b = bits_of(v);
        return (wi >= 0 && wi < 256) ? b : 0u;     // wave-uniform mask
    };

    uint32_t r[2][5];
    vfloat4  raw[2][4];
    #pragma unroll
    for (int c = 0; c < 2; ++c) {
        vfloat4 a[5];
        #pragma unroll
        for (int i = 0; i < 5; ++i) a[i] = ldx(c, w0 - 2 + i);
        #pragma unroll
        for (int t = 0; t < 4; ++t) raw[c][t] = ldx(c, w0 + 3 + t);
        #pragma unroll
        for (int i = 0; i < 5; ++i)
            r[c][i] = row_pack(packb(a[i], w0 - 2 + i), ln);
    }

    #pragma unroll
    for (int g = 0; g < CH1; g += 4) {
        vfloat4 n[2][4];
        if (g + 4 < CH1) {                          // no dead tail loads
            #pragma unroll
            for (int c = 0; c < 2; ++c)
                #pragma unroll
                for (int t = 0; t < 4; ++t) n[c][t] = ldx(c, w0 + g + 7 + t);
        }
        #pragma unroll
        for (int c = 0; c < 2; ++c) {
            #pragma unroll
            for (int j = 0; j < 4; ++j) {
                const int w = w0 + g + j;
                uint32_t rn = row_pack(packb(raw[c][j], w + 3), ln);
                uint32_t m0 = r[c][0] & 0x7f7f7f7fu, m1 = r[c][1] & 0x7f7f7f7fu,
                         m2 = r[c][2] & 0x7f7f7f7fu, m3 = r[c][3] & 0x7f7f7f7fu,
                         m4 = r[c][4] & 0x7f7f7f7fu;
                uint32_t s = m0 + (m1 << 1) + m2 * 3u + (m3 << 1) + m4;  // <=81
                if (w == 0 || w == 255) s -= m2;    // w boundary correction
                s |= (r[c][2] & 0x80808080u);       // carry center x-bits
                os[c][w * 64 + ln] = s;             // regular store: K2 re-reads
                r[c][0] = r[c][1]; r[c][1] = r[c][2];
                r[c][2] = r[c][3]; r[c][3] = r[c][4]; r[c][4] = rn;
            }
        }
        if (g + 4 < CH1) {
            #pragma unroll
            for (int c = 0; c < 2; ++c)
                #pragma unroll
                for (int t = 0; t < 4; ++t) raw[c][t] = n[c][t];
        }
    }
}

// K2: h-axis filter + integer threshold, TRANSPOSED: wave owns
// (slab=(bi,hi), 16-w chunk); marches along w -> contiguous write stream.
__global__ __launch_bounds__(256) void skel_k2(const uint32_t* __restrict__ ws,
                                               vfloat4* __restrict__ out) {
    const int ln    = threadIdx.x & 63;
    const int wid   = (blockIdx.x << 2) | (threadIdx.x >> 6);  // 0..8191
    const int chunk = wid & (NCW2 - 1);
    const int slab  = wid >> 4;            // bi*256 + hi, 0..511
    const int hi    = slab & 255, bi = slab >> 8;
    const int w0    = chunk * CW2;

    // 5 wave-uniform h-rows (clamped addr + zero-mask for OOB)
    uint32_t rowbase[5];                   // u32 index of (bi,hk) row at w0
    uint32_t rmask[5];                     // 0x7f7f7f7f if in-range else 0
    #pragma unroll
    for (int k = 0; k < 5; ++k) {
        const int hk = hi - 2 + k;
        const int hc = hk < 0 ? 0 : (hk > 255 ? 255 : hk);
        rowbase[k] = ((uint32_t)bi * 256u + (uint32_t)hc) * 16384u
                   + (uint32_t)w0 * 64u + (uint32_t)ln;
        rmask[k]   = (hk >= 0 && hk <= 255) ? 0x7f7f7f7fu : 0u;
    }
    const bool hbound = (hi == 0 || hi == 255);
    const uint32_t obase = (uint32_t)slab * 16384u + (uint32_t)w0 * 64u
                         + (uint32_t)ln;

    uint32_t cur[5], nxt[5];
    #pragma unroll
    for (int k = 0; k < 5; ++k) { cur[k] = ws[rowbase[k]]; nxt[k] = cur[k]; }

    #pragma unroll
    for (int j = 0; j < CW2; ++j) {
        if (j + 1 < CW2) {                          // 1-deep prefetch along w
            #pragma unroll
            for (int k = 0; k < 5; ++k)
                nxt[k] = ws[rowbase[k] + (uint32_t)(j + 1) * 64u];
        }
        const uint32_t m0 = cur[0] & rmask[0], m1 = cur[1] & rmask[1],
                       m2 = cur[2] & rmask[2], m3 = cur[3] & rmask[3],
                       m4 = cur[4] & rmask[4];
        // 16-bit SWAR over even/odd bytes; max 729 per field
        const uint32_t e0 = m0 & 0x00ff00ffu, e1 = m1 & 0x00ff00ffu,
                       e2 = m2 & 0x00ff00ffu, e3 = m3 & 0x00ff00ffu,
                       e4 = m4 & 0x00ff00ffu;
        const uint32_t o0 = (m0 >> 8) & 0x00ff00ffu, o1 = (m1 >> 8) & 0x00ff00ffu,
                       o2 = (m2 >> 8) & 0x00ff00ffu, o3 = (m3 >> 8) & 0x00ff00ffu,
                       o4 = (m4 >> 8) & 0x00ff00ffu;
        uint32_t ae = e0 + (e1 << 1) + e2 * 3u + (e3 << 1) + e4;
        uint32_t ao = o0 + (o1 << 1) + o2 * 3u + (o3 << 1) + o4;
        if (hbound) { ae -= e2; ao -= o2; }         // h boundary correction
        const uint32_t xb = cur[2];                 // center row (always valid)
        vfloat4 o;
        o.x = ((ae & 0xffffu) >= 9u && !((xb >> 7)  & 1u)) ? 1.0f : 0.0f;
        o.y = ((ao & 0xffffu) >= 9u && !((xb >> 15) & 1u)) ? 1.0f : 0.0f;
        o.z = ((ae >> 16)     >= 9u && !((xb >> 23) & 1u)) ? 1.0f : 0.0f;
        o.w = ((ao >> 16)     >= 9u && !((xb >> 31) & 1u)) ? 1.0f : 0.0f;
        __builtin_nontemporal_store(o, &out[obase + (uint32_t)j * 64u]);
        #pragma unroll
        for (int k = 0; k < 5; ++k) cur[k] = nxt[k];
    }
}

extern "C" void kernel_launch(void* const* d_in, const int* in_sizes, int n_in,
                              void* d_out, int out_size, void* d_ws, size_t ws_size,
                              hipStream_t stream) {
    const float* x = (const float*)d_in[0];
    uint32_t* ws = (uint32_t*)d_ws;            // needs 32 MiB scratch
    skel_k1<<<BLOCKS_K1, 256, 0, stream>>>(x, ws);
    skel_k2<<<BLOCKS_K2, 256, 0, stream>>>(ws, (vfloat4*)d_out);
}

// Round 7
// 240.032 us; speedup vs baseline: 1.0384x; 1.0384x over previous
//
#include <hip/hip_runtime.h>
#include <stdint.h>

// DifferentiableSkeletonize on (2,1,256,256,256) binary fp32 mask — single
// pass, LDS-tiled. dilated = avgpool3(avgpool3(x)) = separable 5-tap
// [1,2,3,2,1]/9 per axis (zero-extended); boundary planes (i=0,255) subtract
// one extra center tap. n = integer numerator in [0,729]. Pointwise tail is
// EXACTLY out = (x==0 && n>=9) ? 1.0f : 0.0f (verified, absmax 0).
//
// Block = 4 waves owns 16h x 8w x 256d outputs.
//  Phase 1: 20 rows (16+4 halo) x 8 cols of d+w-filtered bytes -> 40KB LDS.
//           Each row's d-filter (DPP row_pack) computed ONCE (1.875x total
//           redundancy vs 4.5x of the failed in-register fused kernel).
//  Phase 2: h-SWAR + integer threshold from LDS; 1KB-contiguous nontemporal
//           stores marching w (8KB stream per wave-row).
// No ws round-trip (saves 64 MiB traffic + a launch vs two-phase).
// LDS 40KB -> 4 blocks/CU = 16 waves/CU = 4/SIMD.

typedef float vfloat4 __attribute__((ext_vector_type(4)));

#define HB 16        // output h rows per block
#define WB 8         // output w cols per block
#define NR 20        // HB + 4 halo rows in LDS
#define NC 12        // WB + 4 packed columns per row
#define BLOCKS 1024  // 2 bi * 16 hblk * 32 wchunk

// d-axis filter: lane ln owns bytes for d = 4ln..4ln+3. b = 4 packed x-bits.
// wave_shr1 (0x138): lane i <- i-1 (lane0 -> 0)  == shfl_up(b,1)
// wave_shl1 (0x130): lane i <- i+1 (lane63 -> 0) == shfl_down(b,1)
__device__ __forceinline__ uint32_t row_pack(uint32_t b, const int ln) {
    uint32_t up = (uint32_t)__builtin_amdgcn_update_dpp(
        0, (int)b, 0x138, 0xf, 0xf, true);
    uint32_t dn = (uint32_t)__builtin_amdgcn_update_dpp(
        0, (int)b, 0x130, 0xf, 0xf, true);
    uint64_t W = (uint64_t)(up >> 16) | ((uint64_t)b << 16)
               | ((uint64_t)(dn & 0xffffu) << 48);
    uint64_t S = W + ((W >> 8) << 1) + (W >> 16) * 3u + ((W >> 24) << 1) + (W >> 32);
    uint32_t n = (uint32_t)S;
    if (ln == 0)  n -= (b & 0xffu);        // d==0 boundary correction
    if (ln == 63) n -= (b & 0xff000000u);  // d==255
    return n | (b << 7);                   // x-bit -> bit7 of each byte
}

__device__ __forceinline__ uint32_t bits_of(const vfloat4 v) {
    return (v.x > 0.5f ? 0x1u : 0u) | (v.y > 0.5f ? 0x100u : 0u)
         | (v.z > 0.5f ? 0x10000u : 0u) | (v.w > 0.5f ? 0x1000000u : 0u);
}

__global__ __launch_bounds__(256) void skel_one(const float* __restrict__ x,
                                                vfloat4* __restrict__ out) {
    __shared__ uint32_t sm[NR * WB * 64];          // 40960 B
    const int ln = threadIdx.x & 63;
    const int wv = threadIdx.x >> 6;
    const int bid = blockIdx.x;
    const int wchunk =  bid       & 31;
    const int hblk   = (bid >> 5) & 15;
    const int bi     =  bid >> 9;
    const int w0 = wchunk * WB;
    const int h0 = hblk * HB;

    const vfloat4* xb = (const vfloat4*)x + ((size_t)bi << 22);  // 256^3/4
    vfloat4* ob = out + ((size_t)bi << 22);

    // ---- phase 1: d+w filter for rows r0..r0+4 (this wave) -> LDS ----
    const int r0 = wv * 5;
    vfloat4 A[NC];
    #pragma unroll
    for (int rr = 0; rr < 5; ++rr) {
        const int r = r0 + rr;
        const int h = h0 - 2 + r;
        const int hc = h < 0 ? 0 : (h > 255 ? 255 : h);
        const uint32_t hok = (h >= 0 && h <= 255) ? 0xffffffffu : 0u;
        // 12 column loads in flight (48 VGPR of MLP)
        #pragma unroll
        for (int i = 0; i < NC; ++i) {
            const int w = w0 - 2 + i;
            const int wc = w < 0 ? 0 : (w > 255 ? 255 : w);
            A[i] = xb[(uint32_t)hc * 16384u + (uint32_t)wc * 64u + (uint32_t)ln];
        }
        uint32_t p[NC];
        #pragma unroll
        for (int i = 0; i < NC; ++i) {
            const int w = w0 - 2 + i;
            uint32_t b = bits_of(A[i]);
            b = (w >= 0 && w <= 255) ? (b & hok) : 0u;     // wave-uniform masks
            p[i] = row_pack(b, ln);
        }
        #pragma unroll
        for (int c = 0; c < WB; ++c) {
            const int w = w0 + c;
            const uint32_t m0 = p[c]   & 0x7f7f7f7fu, m1 = p[c+1] & 0x7f7f7f7fu,
                           m2 = p[c+2] & 0x7f7f7f7fu, m3 = p[c+3] & 0x7f7f7f7fu,
                           m4 = p[c+4] & 0x7f7f7f7fu;
            uint32_t s = m0 + (m1 << 1) + m2 * 3u + (m3 << 1) + m4;  // <=81/byte
            if (w == 0 || w == 255) s -= m2;               // w boundary
            s |= (p[c+2] & 0x80808080u);                   // carry center x-bit
            sm[((uint32_t)r * WB + (uint32_t)c) * 64u + (uint32_t)ln] = s;
        }
    }

    __syncthreads();

    // ---- phase 2: h-SWAR + threshold for output rows k0..k0+3 (this wave) ----
    #pragma unroll
    for (int kk = 0; kk < 4; ++kk) {
        const int k = wv * 4 + kk;                         // 0..15
        const int h = h0 + k;
        const bool hbnd = (h == 0 || h == 255);
        #pragma unroll
        for (int c = 0; c < WB; ++c) {
            uint32_t q[5];
            #pragma unroll
            for (int s5 = 0; s5 < 5; ++s5)
                q[s5] = sm[((uint32_t)(k + s5) * WB + (uint32_t)c) * 64u
                           + (uint32_t)ln];
            const uint32_t m0 = q[0] & 0x7f7f7f7fu, m1 = q[1] & 0x7f7f7f7fu,
                           m2 = q[2] & 0x7f7f7f7fu, m3 = q[3] & 0x7f7f7f7fu,
                           m4 = q[4] & 0x7f7f7f7fu;
            // 16-bit SWAR over even/odd bytes; max 729 per field
            const uint32_t e0 = m0 & 0x00ff00ffu, e1 = m1 & 0x00ff00ffu,
                           e2 = m2 & 0x00ff00ffu, e3 = m3 & 0x00ff00ffu,
                           e4 = m4 & 0x00ff00ffu;
            const uint32_t o0 = (m0 >> 8) & 0x00ff00ffu, o1 = (m1 >> 8) & 0x00ff00ffu,
                           o2 = (m2 >> 8) & 0x00ff00ffu, o3 = (m3 >> 8) & 0x00ff00ffu,
                           o4 = (m4 >> 8) & 0x00ff00ffu;
            uint32_t ae = e0 + (e1 << 1) + e2 * 3u + (e3 << 1) + e4;
            uint32_t ao = o0 + (o1 << 1) + o2 * 3u + (o3 << 1) + o4;
            if (hbnd) { ae -= e2; ao -= o2; }              // h boundary
            const uint32_t cen = q[2];                     // center x-bits
            vfloat4 o;
            o.x = ((ae & 0xffffu) >= 9u && !((cen >> 7)  & 1u)) ? 1.0f : 0.0f;
            o.y = ((ao & 0xffffu) >= 9u && !((cen >> 15) & 1u)) ? 1.0f : 0.0f;
            o.z = ((ae >> 16)     >= 9u && !((cen >> 23) & 1u)) ? 1.0f : 0.0f;
            o.w = ((ao >> 16)     >= 9u && !((cen >> 31) & 1u)) ? 1.0f : 0.0f;
            __builtin_nontemporal_store(
                o, &ob[(uint32_t)h * 16384u + (uint32_t)(w0 + c) * 64u
                       + (uint32_t)ln]);
        }
    }
}

extern "C" void kernel_launch(void* const* d_in, const int* in_sizes, int n_in,
                              void* d_out, int out_size, void* d_ws, size_t ws_size,
                              hipStream_t stream) {
    const float* x = (const float*)d_in[0];
    (void)d_ws; (void)ws_size; (void)in_sizes; (void)n_in; (void)out_size;
    skel_one<<<BLOCKS, 256, 0, stream>>>(x, (vfloat4*)d_out);
}

// Round 8
// 236.428 us; speedup vs baseline: 1.0542x; 1.0152x over previous
//
#include <hip/hip_runtime.h>
#include <stdint.h>

// DifferentiableSkeletonize on (2,1,256,256,256) binary fp32 mask — single
// pass, LDS-tiled. dilated = avgpool3(avgpool3(x)) = separable 5-tap
// [1,2,3,2,1]/9 per axis (zero-extended); boundary planes (i=0,255) subtract
// one extra center tap. n = integer numerator in [0,729]. Pointwise tail is
// EXACTLY out = (x==0 && n>=9) ? 1.0f : 0.0f (verified, absmax 0).
//
// Round-8: tile 8h x 8w x 256d per block (was 16h x 8w). LDS 24 KB ->
// 6 blocks/CU resident (was 4), grid 2048 -> backfill + phase stagger;
// round-7 counters showed traffic already minimal (246 MB) but BW at 45%
// from lockstep phases at 4 blocks/CU. Chunked XCD swizzle keeps w-adjacent
// tiles (shared 4-col halo) on the same XCD's L2.

typedef float vfloat4 __attribute__((ext_vector_type(4)));

#define HB 8         // output h rows per block
#define WB 8         // output w cols per block
#define NR 12        // HB + 4 halo rows in LDS
#define NC 12        // WB + 4 packed columns per row
#define BLOCKS 2048  // 2 bi * 32 hblk * 32 wchunk

// d-axis filter: lane ln owns bytes for d = 4ln..4ln+3. b = 4 packed x-bits.
// wave_shr1 (0x138): lane i <- i-1 (lane0 -> 0)  == shfl_up(b,1)
// wave_shl1 (0x130): lane i <- i+1 (lane63 -> 0) == shfl_down(b,1)
__device__ __forceinline__ uint32_t row_pack(uint32_t b, const int ln) {
    uint32_t up = (uint32_t)__builtin_amdgcn_update_dpp(
        0, (int)b, 0x138, 0xf, 0xf, true);
    uint32_t dn = (uint32_t)__builtin_amdgcn_update_dpp(
        0, (int)b, 0x130, 0xf, 0xf, true);
    uint64_t W = (uint64_t)(up >> 16) | ((uint64_t)b << 16)
               | ((uint64_t)(dn & 0xffffu) << 48);
    uint64_t S = W + ((W >> 8) << 1) + (W >> 16) * 3u + ((W >> 24) << 1) + (W >> 32);
    uint32_t n = (uint32_t)S;
    if (ln == 0)  n -= (b & 0xffu);        // d==0 boundary correction
    if (ln == 63) n -= (b & 0xff000000u);  // d==255
    return n | (b << 7);                   // x-bit -> bit7 of each byte
}

__device__ __forceinline__ uint32_t bits_of(const vfloat4 v) {
    return (v.x > 0.5f ? 0x1u : 0u) | (v.y > 0.5f ? 0x100u : 0u)
         | (v.z > 0.5f ? 0x10000u : 0u) | (v.w > 0.5f ? 0x1000000u : 0u);
}

__global__ __launch_bounds__(256) void skel_one(const float* __restrict__ x,
                                                vfloat4* __restrict__ out) {
    __shared__ uint32_t sm[NR * WB * 64];          // 24576 B
    const int ln = threadIdx.x & 63;
    const int wv = threadIdx.x >> 6;

    // chunked XCD swizzle (bijective: 2048 % 8 == 0): each XCD gets a
    // contiguous run of 256 logical tiles -> w-neighbors share its L2.
    const int bid = (int)((blockIdx.x & 7u) * (BLOCKS / 8) + (blockIdx.x >> 3));
    const int wchunk =  bid       & 31;
    const int hblk   = (bid >> 5) & 31;
    const int bi     =  bid >> 10;
    const int w0 = wchunk * WB;
    const int h0 = hblk * HB;

    const vfloat4* xb = (const vfloat4*)x + ((size_t)bi << 22);  // 256^3/4
    vfloat4* ob = out + ((size_t)bi << 22);

    // ---- phase 1: d+w filter for rows r0..r0+2 (this wave) -> LDS ----
    const int r0 = wv * 3;                         // 12 rows / 4 waves
    vfloat4 A[NC];
    #pragma unroll
    for (int rr = 0; rr < 3; ++rr) {
        const int r = r0 + rr;
        const int h = h0 - 2 + r;
        const int hc = h < 0 ? 0 : (h > 255 ? 255 : h);
        const uint32_t hok = (h >= 0 && h <= 255) ? 0xffffffffu : 0u;
        // 12 column loads in flight (48 VGPR of MLP)
        #pragma unroll
        for (int i = 0; i < NC; ++i) {
            const int w = w0 - 2 + i;
            const int wc = w < 0 ? 0 : (w > 255 ? 255 : w);
            A[i] = xb[(uint32_t)hc * 16384u + (uint32_t)wc * 64u + (uint32_t)ln];
        }
        uint32_t p[NC];
        #pragma unroll
        for (int i = 0; i < NC; ++i) {
            const int w = w0 - 2 + i;
            uint32_t b = bits_of(A[i]);
            b = (w >= 0 && w <= 255) ? (b & hok) : 0u;     // wave-uniform masks
            p[i] = row_pack(b, ln);
        }
        #pragma unroll
        for (int c = 0; c < WB; ++c) {
            const int w = w0 + c;
            const uint32_t m0 = p[c]   & 0x7f7f7f7fu, m1 = p[c+1] & 0x7f7f7f7fu,
                           m2 = p[c+2] & 0x7f7f7f7fu, m3 = p[c+3] & 0x7f7f7f7fu,
                           m4 = p[c+4] & 0x7f7f7f7fu;
            uint32_t s = m0 + (m1 << 1) + m2 * 3u + (m3 << 1) + m4;  // <=81/byte
            if (w == 0 || w == 255) s -= m2;               // w boundary
            s |= (p[c+2] & 0x80808080u);                   // carry center x-bit
            sm[((uint32_t)r * WB + (uint32_t)c) * 64u + (uint32_t)ln] = s;
        }
    }

    __syncthreads();

    // ---- phase 2: h-SWAR + threshold for output rows k0..k0+1 (this wave) ----
    #pragma unroll
    for (int kk = 0; kk < 2; ++kk) {
        const int k = wv * 2 + kk;                         // 0..7
        const int h = h0 + k;
        const bool hbnd = (h == 0 || h == 255);
        #pragma unroll
        for (int c = 0; c < WB; ++c) {
            uint32_t q[5];
            #pragma unroll
            for (int s5 = 0; s5 < 5; ++s5)
                q[s5] = sm[((uint32_t)(k + s5) * WB + (uint32_t)c) * 64u
                           + (uint32_t)ln];
            const uint32_t m0 = q[0] & 0x7f7f7f7fu, m1 = q[1] & 0x7f7f7f7fu,
                           m2 = q[2] & 0x7f7f7f7fu, m3 = q[3] & 0x7f7f7f7fu,
                           m4 = q[4] & 0x7f7f7f7fu;
            // 16-bit SWAR over even/odd bytes; max 729 per field
            const uint32_t e0 = m0 & 0x00ff00ffu, e1 = m1 & 0x00ff00ffu,
                           e2 = m2 & 0x00ff00ffu, e3 = m3 & 0x00ff00ffu,
                           e4 = m4 & 0x00ff00ffu;
            const uint32_t o0 = (m0 >> 8) & 0x00ff00ffu, o1 = (m1 >> 8) & 0x00ff00ffu,
                           o2 = (m2 >> 8) & 0x00ff00ffu, o3 = (m3 >> 8) & 0x00ff00ffu,
                           o4 = (m4 >> 8) & 0x00ff00ffu;
            uint32_t ae = e0 + (e1 << 1) + e2 * 3u + (e3 << 1) + e4;
            uint32_t ao = o0 + (o1 << 1) + o2 * 3u + (o3 << 1) + o4;
            if (hbnd) { ae -= e2; ao -= o2; }              // h boundary
            const uint32_t cen = q[2];                     // center x-bits
            vfloat4 o;
            o.x = ((ae & 0xffffu) >= 9u && !((cen >> 7)  & 1u)) ? 1.0f : 0.0f;
            o.y = ((ao & 0xffffu) >= 9u && !((cen >> 15) & 1u)) ? 1.0f : 0.0f;
            o.z = ((ae >> 16)     >= 9u && !((cen >> 23) & 1u)) ? 1.0f : 0.0f;
            o.w = ((ao >> 16)     >= 9u && !((cen >> 31) & 1u)) ? 1.0f : 0.0f;
            __builtin_nontemporal_store(
                o, &ob[(uint32_t)h * 16384u + (uint32_t)(w0 + c) * 64u
                       + (uint32_t)ln]);
        }
    }
}

extern "C" void kernel_launch(void* const* d_in, const int* in_sizes, int n_in,
                              void* d_out, int out_size, void* d_ws, size_t ws_size,
                              hipStream_t stream) {
    const float* x = (const float*)d_in[0];
    (void)d_ws; (void)ws_size; (void)in_sizes; (void)n_in; (void)out_size;
    skel_one<<<BLOCKS, 256, 0, stream>>>(x, (vfloat4*)d_out);
}